// Round 8
// baseline (333.454 us; speedup 1.0000x reference)
//
#include <hip/hip_runtime.h>
#include <stdint.h>

#define B_ 2
#define S_ 2048
#define E_ 1024
#define H_ 16
#define D_ 64
// 1/sqrt(64) * log2(e): scores in log2 domain -> P = exp2(S)
#define QSCALE_ 0.18033688011112042f

typedef __attribute__((ext_vector_type(8))) short short8;
typedef __attribute__((ext_vector_type(4))) float f32x4;
typedef __attribute__((ext_vector_type(16))) float f32x16;
typedef unsigned int u32;

__device__ __forceinline__ unsigned short f2bf(float x) {
    union { float f; u32 u; } v; v.f = x;
    u32 r = v.u + 0x7fffu + ((v.u >> 16) & 1u);
    return (unsigned short)(r >> 16);
}
__device__ __forceinline__ u32 fbits(float x) {
    union { float f; u32 u; } v; v.f = x; return v.u;
}
// pack two f32 -> two bf16 (truncation; bias cancels in softmax ratio)
__device__ __forceinline__ u32 pkbf(float lo, float hi) {
    return __builtin_amdgcn_perm(fbits(hi), fbits(lo), 0x07060302u);
}

__device__ __forceinline__ f32x4 mfma16(short8 a, short8 b, f32x4 c) {
    return __builtin_amdgcn_mfma_f32_16x16x32_bf16(a, b, c, 0, 0, 0);
}
__device__ __forceinline__ f32x16 mfma32(short8 a, short8 b, f32x16 c) {
    return __builtin_amdgcn_mfma_f32_32x32x16_bf16(a, b, c, 0, 0, 0);
}

__device__ __forceinline__ void gld16(const unsigned short* g, unsigned short* l) {
    __builtin_amdgcn_global_load_lds(
        (const __attribute__((address_space(1))) u32*)g,
        (__attribute__((address_space(3))) u32*)l, 16, 0, 0);
}

// ---------------------------------------------------------------------------
// Kernel 0: fp32 -> bf16 of x, w_qkv, w_out.
// ---------------------------------------------------------------------------
__global__ __launch_bounds__(256) void cvt_kernel(
    const float* __restrict__ x, const float* __restrict__ wq,
    const float* __restrict__ wo,
    unsigned short* __restrict__ xb, unsigned short* __restrict__ wqb,
    unsigned short* __restrict__ wob)
{
    const long i8 = ((long)blockIdx.x * 256 + threadIdx.x) * 8;
    const float* src; unsigned short* dst; long off;
    if (i8 < 4194304)      { src = x;  dst = xb;  off = i8; }
    else if (i8 < 7340032) { src = wq; dst = wqb; off = i8 - 4194304; }
    else                   { src = wo; dst = wob; off = i8 - 7340032; }
    f32x4 a = *(const f32x4*)(src + off);
    f32x4 b = *(const f32x4*)(src + off + 4);
    short8 o;
    o[0] = (short)f2bf(a[0]); o[1] = (short)f2bf(a[1]);
    o[2] = (short)f2bf(a[2]); o[3] = (short)f2bf(a[3]);
    o[4] = (short)f2bf(b[0]); o[5] = (short)f2bf(b[1]);
    o[6] = (short)f2bf(b[2]); o[7] = (short)f2bf(b[3]);
    *(short8*)(dst + off) = o;
}

// ---------------------------------------------------------------------------
// Kernel 1: QKV projection (round-6 version, m97 BK=32 staging).
// Q (pre-scaled) / K stored direct.  V blocks (n0>=2048) via LDS transpose,
// stored key-PERMUTED (quads {0,2,1,3} per 16) so attn PV B-frags are b128.
// ---------------------------------------------------------------------------
__global__ __launch_bounds__(256) void qkv_gemm_kernel(
    const unsigned short* __restrict__ x, const unsigned short* __restrict__ w,
    const float* __restrict__ bias,
    unsigned short* __restrict__ Qg, unsigned short* __restrict__ Kg,
    unsigned short* __restrict__ Vtg)
{
    __shared__ __attribute__((aligned(16))) unsigned char smem[16896];
    __shared__ float biass[128];
    unsigned short* As = (unsigned short*)smem;
    unsigned short* Bs = (unsigned short*)(smem + 8192);
    float* Tr = (float*)smem;

    const int t = threadIdx.x;
    const int m0 = blockIdx.x * 128;
    const int n0 = blockIdx.y * 128;
    const int lane = t & 63;
    const int wv = t >> 6;
    const int g = lane >> 4;
    const int l15 = lane & 15;
    const int wm = (wv >> 1) * 64;
    const int wn = (wv & 1) * 64;
    const int rloc = lane >> 2;
    const int cg = (lane & 3) ^ ((lane >> 3) & 3);
    const int rsw = (g ^ ((l15 >> 1) & 3)) * 8;

    if (t < 128) biass[t] = bias[n0 + t];

    f32x4 acc[4][4];
#pragma unroll
    for (int i = 0; i < 4; ++i)
#pragma unroll
        for (int j = 0; j < 4; ++j)
            acc[i][j] = (f32x4){0.f, 0.f, 0.f, 0.f};

    for (int kt = 0; kt < E_; kt += 32) {
        __syncthreads();
#pragma unroll
        for (int j = 0; j < 2; ++j) {
            const int rb = 32 * wv + 16 * j;
            gld16(x + (m0 + rb + rloc) * E_ + kt + cg * 8, &As[rb * 32]);
            gld16(w + (n0 + rb + rloc) * E_ + kt + cg * 8, &Bs[rb * 32]);
        }
        __syncthreads();

        short8 af[4], bf[4];
#pragma unroll
        for (int mt = 0; mt < 4; ++mt)
            af[mt] = *(const short8*)&As[(wm + mt * 16 + l15) * 32 + rsw];
#pragma unroll
        for (int nt = 0; nt < 4; ++nt)
            bf[nt] = *(const short8*)&Bs[(wn + nt * 16 + l15) * 32 + rsw];
#pragma unroll
        for (int mt = 0; mt < 4; ++mt)
#pragma unroll
            for (int nt = 0; nt < 4; ++nt)
                acc[mt][nt] = mfma16(af[mt], bf[nt], acc[mt][nt]);
    }

    if (n0 < 2048) {
        // -------- Q / K blocks: direct stores --------
#pragma unroll
        for (int mt = 0; mt < 4; ++mt) {
#pragma unroll
            for (int nt = 0; nt < 4; ++nt) {
                const int col = n0 + wn + nt * 16 + l15;
                const int which = col >> 10;          // 0=Q 1=K (wave-uniform)
                const int cr = col & 1023;
                const int h = cr >> 6;
                const int d = cr & 63;
                const float bia = biass[col - n0];
#pragma unroll
                for (int i = 0; i < 4; ++i) {
                    const int row = m0 + wm + mt * 16 + g * 4 + i;
                    const int bb = row >> 11;
                    const int s = row & 2047;
                    const int bh = bb * H_ + h;
                    const float v = acc[mt][nt][i] + bia;
                    if (which == 0)
                        Qg[(bh * S_ + s) * D_ + d] = f2bf(v * QSCALE_);
                    else
                        Kg[(bh * S_ + s) * D_ + d] = f2bf(v);
                }
            }
        }
    } else {
        // -------- V blocks: LDS-transpose slabs, permuted coalesced stores --
        const int bb = m0 >> 11;
        const int s0 = m0 & 2047;
        const int dth = t >> 3;        // 0..31 : d within slab
        const int sc = t & 7;          // 0..7  : s-chunk of 16
#pragma unroll
        for (int sl = 0; sl < 4; ++sl) {
            __syncthreads();
            if ((wv & 1) == (sl >> 1)) {
#pragma unroll
                for (int q = 0; q < 2; ++q) {
                    const int nt = (sl & 1) * 2 + q;
                    const float bia = biass[wn + nt * 16 + l15];
                    const int dloc = q * 16 + l15;
#pragma unroll
                    for (int mt = 0; mt < 4; ++mt)
#pragma unroll
                        for (int i = 0; i < 4; ++i)
                            Tr[(wm + mt * 16 + g * 4 + i) * 33 + dloc] =
                                acc[mt][nt][i] + bia;
                }
            }
            __syncthreads();
            const int dglob = (n0 - 2048) + sl * 32 + dth;
            const int h = dglob >> 6;
            const int dd = dglob & 63;
            unsigned short* dst =
                Vtg + ((long)(bb * H_ + h) * D_ + dd) * S_ + s0 + sc * 16;
            // key-permuted: dst quads get src quads {0, 2, 1, 3}
            short8 o0, o1;
#pragma unroll
            for (int j = 0; j < 4; ++j) {
                o0[j]     = (short)f2bf(Tr[(sc * 16 + j)      * 33 + dth]);
                o0[4 + j] = (short)f2bf(Tr[(sc * 16 + 8 + j)  * 33 + dth]);
                o1[j]     = (short)f2bf(Tr[(sc * 16 + 4 + j)  * 33 + dth]);
                o1[4 + j] = (short)f2bf(Tr[(sc * 16 + 12 + j) * 33 + dth]);
            }
            *(short8*)dst = o0;
            *(short8*)(dst + 8) = o1;
        }
    }
}

// ---------------------------------------------------------------------------
// Kernel 2: flash attention, key-split x4, ZERO-LDS main loop.
// Block = 4 waves, all on the same 64-q tile; wave wv handles keys
// [wv*512, wv*512+512).  K/V fragments loaded straight from global (same
// bytes the old LDS staging produced); no barriers in the main loop.
// Partial (O, lsum) combined via LDS atomicAdd (no-max softmax => partials
// combine by pure addition).  grid (32,32) = 1024 blocks, 4096 waves.
// ---------------------------------------------------------------------------
__global__ __launch_bounds__(256, 3) void attn_kernel(
    const unsigned short* __restrict__ Qg, const unsigned short* __restrict__ Kg,
    const unsigned short* __restrict__ Vtg, unsigned short* __restrict__ ctx)
{
    __shared__ float Oacc[64 * 64];    // 16 KB fp32 combine accumulator
    __shared__ float lsumW[4][64];     // per-wave partial denominators

    const int t = threadIdx.x;
    const int lane = t & 63;
    const int wv = t >> 6;              // 0..3 key-split index
    const int qb = blockIdx.x;          // 0..31, q-tile of 64
    const int bh = blockIdx.y;          // 0..31
    const int bb = bh >> 4;
    const int hh = bh & 15;
    const int l31 = lane & 31;
    const int hf = lane >> 5;

    // zero the combine accumulator (4096 floats / 256 threads)
    {
        f32x4 z = (f32x4){0.f, 0.f, 0.f, 0.f};
#pragma unroll
        for (int i = 0; i < 4; ++i)
            *(f32x4*)&Oacc[t * 16 + i * 4] = z;
    }
    __syncthreads();

    // Q B-frags (all 4 waves share the q-tile): qa[qh][kc]
    short8 qa[2][4];
#pragma unroll
    for (int qh = 0; qh < 2; ++qh)
#pragma unroll
        for (int kc = 0; kc < 4; ++kc)
            qa[qh][kc] = *(const short8*)(
                Qg + (bh * S_ + qb * 64 + qh * 32 + l31) * D_ + kc * 16 + hf * 8);

    f32x16 O[2][2];     // [qh][dt]
    float lsum[2] = {0.f, 0.f};
#pragma unroll
    for (int qh = 0; qh < 2; ++qh)
#pragma unroll
        for (int dt = 0; dt < 2; ++dt)
#pragma unroll
            for (int r = 0; r < 16; ++r) O[qh][dt][r] = 0.f;

    // per-lane base pointers
    const unsigned short* Kbase = Kg + (bh * S_ + l31) * D_ + hf * 8;
    const unsigned short* Vb0 = Vtg + (bh * D_ + l31) * S_;
    const unsigned short* Vb1 = Vtg + (bh * D_ + 32 + l31) * S_;

    for (int i = 0; i < 8; ++i) {
        const int kb = wv * 8 + i;      // 64-key tile index
        const int ko = kb * 64;         // key offset
#pragma unroll
        for (int kt = 0; kt < 2; ++kt) {
            // K A-frags: K[key = ko + kt*32 + l31][d chunk 2kc+hf]
            short8 kf[4];
#pragma unroll
            for (int kc = 0; kc < 4; ++kc)
                kf[kc] = *(const short8*)(Kbase + (ko + kt * 32) * D_ + kc * 16);

            f32x16 st[2];
#pragma unroll
            for (int qh = 0; qh < 2; ++qh) {
                f32x16 s;
#pragma unroll
                for (int r = 0; r < 16; ++r) s[r] = 0.f;
#pragma unroll
                for (int kc = 0; kc < 4; ++kc)
                    s = mfma32(kf[kc], qa[qh][kc], s);
                st[qh] = s;
            }

            // exp2 -> pack -> PV; V^T is key-permuted so B-frags are b128
#pragma unroll
            for (int cp = 0; cp < 2; ++cp) {
                const int vo = ko + kt * 32 + cp * 16 + hf * 8;
                short8 vb0 = *(const short8*)(Vb0 + vo);
                short8 vb1 = *(const short8*)(Vb1 + vo);
#pragma unroll
                for (int qh = 0; qh < 2; ++qh) {
                    float p[8];
#pragma unroll
                    for (int j = 0; j < 8; ++j)
                        p[j] = __builtin_amdgcn_exp2f(st[qh][8 * cp + j]);
                    lsum[qh] += (p[0] + p[1]) + (p[2] + p[3]) +
                                (p[4] + p[5]) + (p[6] + p[7]);
                    union { short8 s8; u32 u[4]; } pa;
                    pa.u[0] = pkbf(p[0], p[1]);
                    pa.u[1] = pkbf(p[2], p[3]);
                    pa.u[2] = pkbf(p[4], p[5]);
                    pa.u[3] = pkbf(p[6], p[7]);
                    O[qh][0] = mfma32(pa.s8, vb0, O[qh][0]);
                    O[qh][1] = mfma32(pa.s8, vb1, O[qh][1]);
                }
            }
        }
    }

    // partial denominators: fold hf halves, publish per-wave
#pragma unroll
    for (int qh = 0; qh < 2; ++qh) {
        float s = lsum[qh] + __shfl_xor(lsum[qh], 32);
        if (hf == 0) lsumW[wv][qh * 32 + l31] = s;
    }
    // partial O: add into the block accumulator (ds_add_f32)
#pragma unroll
    for (int qh = 0; qh < 2; ++qh)
#pragma unroll
        for (int dt = 0; dt < 2; ++dt)
#pragma unroll
            for (int r = 0; r < 16; ++r) {
                const int q = qh * 32 + 4 * hf + (r & 3) + 8 * (r >> 2);
                atomicAdd(&Oacc[q * 64 + dt * 32 + l31], O[qh][dt][r]);
            }
    __syncthreads();

    // finalize: thread t handles q = t>>2, d-range [ (t&3)*16, +16 )
    {
        const int q = t >> 2;
        const int c = t & 3;
        const float inv = 1.0f / (lsumW[0][q] + lsumW[1][q] +
                                  lsumW[2][q] + lsumW[3][q]);
        const float* src = &Oacc[q * 64 + c * 16];
        unsigned short* dst =
            ctx + ((long)(bb * S_ + qb * 64 + q)) * E_ + hh * D_ + c * 16;
        short8 o0, o1;
#pragma unroll
        for (int j = 0; j < 8; ++j) {
            o0[j] = (short)f2bf(src[j] * inv);
            o1[j] = (short)f2bf(src[8 + j] * inv);
        }
        *(short8*)dst = o0;
        *(short8*)(dst + 8) = o1;
    }
}

// ---------------------------------------------------------------------------
// Kernel 3: output projection, 128x64 tiles, BK=32 (round-6 version).
// ---------------------------------------------------------------------------
__global__ __launch_bounds__(256) void out_gemm_kernel(
    const unsigned short* __restrict__ ctxg, const unsigned short* __restrict__ w,
    const float* __restrict__ bias, float* __restrict__ out)
{
    __shared__ __attribute__((aligned(16))) unsigned short As[128 * 32];
    __shared__ __attribute__((aligned(16))) unsigned short Bs[64 * 32];
    __shared__ float biass[64];

    const int t = threadIdx.x;
    const int m0 = blockIdx.x * 128;
    const int n0 = blockIdx.y * 64;
    const int lane = t & 63;
    const int wv = t >> 6;
    const int g = lane >> 4;
    const int l15 = lane & 15;
    const int wm = (wv >> 1) * 64;
    const int wn = (wv & 1) * 32;
    const int rloc = lane >> 2;
    const int cg = (lane & 3) ^ ((lane >> 3) & 3);
    const int rsw = (g ^ ((l15 >> 1) & 3)) * 8;

    if (t < 64) biass[t] = bias[n0 + t];

    f32x4 acc[4][2];
#pragma unroll
    for (int i = 0; i < 4; ++i)
#pragma unroll
        for (int j = 0; j < 2; ++j)
            acc[i][j] = (f32x4){0.f, 0.f, 0.f, 0.f};

    for (int kt = 0; kt < E_; kt += 32) {
        __syncthreads();
#pragma unroll
        for (int j = 0; j < 2; ++j) {
            const int rb = 32 * wv + 16 * j;
            gld16(ctxg + (m0 + rb + rloc) * E_ + kt + cg * 8, &As[rb * 32]);
        }
        {
            const int rb = 16 * wv;
            gld16(w + (n0 + rb + rloc) * E_ + kt + cg * 8, &Bs[rb * 32]);
        }
        __syncthreads();

        short8 af[4], bf[2];
#pragma unroll
        for (int mt = 0; mt < 4; ++mt)
            af[mt] = *(const short8*)&As[(wm + mt * 16 + l15) * 32 + rsw];
#pragma unroll
        for (int nt = 0; nt < 2; ++nt)
            bf[nt] = *(const short8*)&Bs[(wn + nt * 16 + l15) * 32 + rsw];
#pragma unroll
        for (int mt = 0; mt < 4; ++mt)
#pragma unroll
            for (int nt = 0; nt < 2; ++nt)
                acc[mt][nt] = mfma16(af[mt], bf[nt], acc[mt][nt]);
    }

#pragma unroll
    for (int mt = 0; mt < 4; ++mt) {
#pragma unroll
        for (int nt = 0; nt < 2; ++nt) {
            const int col = n0 + wn + nt * 16 + l15;
            const float bia = biass[col - n0];
#pragma unroll
            for (int i = 0; i < 4; ++i) {
                const int row = m0 + wm + mt * 16 + g * 4 + i;
                out[row * E_ + col] = acc[mt][nt][i] + bia;
            }
        }
    }
}

extern "C" void kernel_launch(void* const* d_in, const int* in_sizes, int n_in,
                              void* d_out, int out_size, void* d_ws, size_t ws_size,
                              hipStream_t stream) {
    const float* x    = (const float*)d_in[0];
    const float* wqkv = (const float*)d_in[1];
    const float* wout = (const float*)d_in[2];
    const float* bqkv = (const float*)d_in[3];
    const float* bout = (const float*)d_in[4];

    unsigned short* Q   = (unsigned short*)d_ws;       // 8 MB
    unsigned short* K   = Q + 4194304;                 // 8 MB
    unsigned short* Vt  = K + 4194304;                 // 8 MB (key-permuted)
    unsigned short* ctx = Vt + 4194304;                // 8 MB (aliased with xb)
    unsigned short* xb  = ctx;                         // dead before attn writes ctx
    unsigned short* wqb = ctx + 4194304;               // 6 MB
    unsigned short* wob = wqb + 3145728;               // 2 MB  (total 40 MB)

    cvt_kernel<<<4096, 256, 0, stream>>>(x, wqkv, wout, xb, wqb, wob);
    qkv_gemm_kernel<<<dim3(32, 24), 256, 0, stream>>>(xb, wqb, bqkv, Q, K, Vt);
    attn_kernel<<<dim3(32, 32), 256, 0, stream>>>(Q, K, Vt, ctx);
    out_gemm_kernel<<<dim3(32, 16), 256, 0, stream>>>(ctx, wob, bout, (float*)d_out);
}

// Round 9
// 180.717 us; speedup vs baseline: 1.8452x; 1.8452x over previous
//
#include <hip/hip_runtime.h>
#include <stdint.h>

#define B_ 2
#define S_ 2048
#define E_ 1024
#define H_ 16
#define D_ 64
// 1/sqrt(64) * log2(e): scores in log2 domain -> P = exp2(S)
#define QSCALE_ 0.18033688011112042f

typedef __attribute__((ext_vector_type(8))) short short8;
typedef __attribute__((ext_vector_type(4))) float f32x4;
typedef __attribute__((ext_vector_type(16))) float f32x16;
typedef unsigned int u32;

__device__ __forceinline__ unsigned short f2bf(float x) {
    union { float f; u32 u; } v; v.f = x;
    u32 r = v.u + 0x7fffu + ((v.u >> 16) & 1u);
    return (unsigned short)(r >> 16);
}
__device__ __forceinline__ u32 fbits(float x) {
    union { float f; u32 u; } v; v.f = x; return v.u;
}
// pack two f32 -> two bf16 (truncation; bias cancels in softmax ratio)
__device__ __forceinline__ u32 pkbf(float lo, float hi) {
    return __builtin_amdgcn_perm(fbits(hi), fbits(lo), 0x07060302u);
}

__device__ __forceinline__ f32x4 mfma16(short8 a, short8 b, f32x4 c) {
    return __builtin_amdgcn_mfma_f32_16x16x32_bf16(a, b, c, 0, 0, 0);
}
__device__ __forceinline__ f32x16 mfma32(short8 a, short8 b, f32x16 c) {
    return __builtin_amdgcn_mfma_f32_32x32x16_bf16(a, b, c, 0, 0, 0);
}

__device__ __forceinline__ void gld16(const unsigned short* g, unsigned short* l) {
    __builtin_amdgcn_global_load_lds(
        (const __attribute__((address_space(1))) u32*)g,
        (__attribute__((address_space(3))) u32*)l, 16, 0, 0);
}

// ---------------------------------------------------------------------------
// Kernel 0: fp32 -> bf16 of x, w_qkv, w_out.
// ---------------------------------------------------------------------------
__global__ __launch_bounds__(256) void cvt_kernel(
    const float* __restrict__ x, const float* __restrict__ wq,
    const float* __restrict__ wo,
    unsigned short* __restrict__ xb, unsigned short* __restrict__ wqb,
    unsigned short* __restrict__ wob)
{
    const long i8 = ((long)blockIdx.x * 256 + threadIdx.x) * 8;
    const float* src; unsigned short* dst; long off;
    if (i8 < 4194304)      { src = x;  dst = xb;  off = i8; }
    else if (i8 < 7340032) { src = wq; dst = wqb; off = i8 - 4194304; }
    else                   { src = wo; dst = wob; off = i8 - 7340032; }
    f32x4 a = *(const f32x4*)(src + off);
    f32x4 b = *(const f32x4*)(src + off + 4);
    short8 o;
    o[0] = (short)f2bf(a[0]); o[1] = (short)f2bf(a[1]);
    o[2] = (short)f2bf(a[2]); o[3] = (short)f2bf(a[3]);
    o[4] = (short)f2bf(b[0]); o[5] = (short)f2bf(b[1]);
    o[6] = (short)f2bf(b[2]); o[7] = (short)f2bf(b[3]);
    *(short8*)(dst + off) = o;
}

// ---------------------------------------------------------------------------
// Kernel 1: QKV projection (m97 BK=32 staging).  C[4096,3072] = Xb * Wqb^T.
// Q (pre-scaled) / K stored direct.  V blocks (n0>=2048) via LDS transpose,
// stored key-PERMUTED (quads {0,2,1,3} per 16) so attn PV B-frags are b128.
// ---------------------------------------------------------------------------
__global__ __launch_bounds__(256) void qkv_gemm_kernel(
    const unsigned short* __restrict__ x, const unsigned short* __restrict__ w,
    const float* __restrict__ bias,
    unsigned short* __restrict__ Qg, unsigned short* __restrict__ Kg,
    unsigned short* __restrict__ Vtg)
{
    __shared__ __attribute__((aligned(16))) unsigned char smem[16896];
    __shared__ float biass[128];
    unsigned short* As = (unsigned short*)smem;
    unsigned short* Bs = (unsigned short*)(smem + 8192);
    float* Tr = (float*)smem;

    const int t = threadIdx.x;
    const int m0 = blockIdx.x * 128;
    const int n0 = blockIdx.y * 128;
    const int lane = t & 63;
    const int wv = t >> 6;
    const int g = lane >> 4;
    const int l15 = lane & 15;
    const int wm = (wv >> 1) * 64;
    const int wn = (wv & 1) * 64;
    const int rloc = lane >> 2;
    const int cg = (lane & 3) ^ ((lane >> 3) & 3);
    const int rsw = (g ^ ((l15 >> 1) & 3)) * 8;

    if (t < 128) biass[t] = bias[n0 + t];

    f32x4 acc[4][4];
#pragma unroll
    for (int i = 0; i < 4; ++i)
#pragma unroll
        for (int j = 0; j < 4; ++j)
            acc[i][j] = (f32x4){0.f, 0.f, 0.f, 0.f};

    for (int kt = 0; kt < E_; kt += 32) {
        __syncthreads();
#pragma unroll
        for (int j = 0; j < 2; ++j) {
            const int rb = 32 * wv + 16 * j;
            gld16(x + (m0 + rb + rloc) * E_ + kt + cg * 8, &As[rb * 32]);
            gld16(w + (n0 + rb + rloc) * E_ + kt + cg * 8, &Bs[rb * 32]);
        }
        __syncthreads();

        short8 af[4], bf[4];
#pragma unroll
        for (int mt = 0; mt < 4; ++mt)
            af[mt] = *(const short8*)&As[(wm + mt * 16 + l15) * 32 + rsw];
#pragma unroll
        for (int nt = 0; nt < 4; ++nt)
            bf[nt] = *(const short8*)&Bs[(wn + nt * 16 + l15) * 32 + rsw];
#pragma unroll
        for (int mt = 0; mt < 4; ++mt)
#pragma unroll
            for (int nt = 0; nt < 4; ++nt)
                acc[mt][nt] = mfma16(af[mt], bf[nt], acc[mt][nt]);
    }

    if (n0 < 2048) {
        // -------- Q / K blocks: direct stores --------
#pragma unroll
        for (int mt = 0; mt < 4; ++mt) {
#pragma unroll
            for (int nt = 0; nt < 4; ++nt) {
                const int col = n0 + wn + nt * 16 + l15;
                const int which = col >> 10;          // 0=Q 1=K (wave-uniform)
                const int cr = col & 1023;
                const int h = cr >> 6;
                const int d = cr & 63;
                const float bia = biass[col - n0];
#pragma unroll
                for (int i = 0; i < 4; ++i) {
                    const int row = m0 + wm + mt * 16 + g * 4 + i;
                    const int bb = row >> 11;
                    const int s = row & 2047;
                    const int bh = bb * H_ + h;
                    const float v = acc[mt][nt][i] + bia;
                    if (which == 0)
                        Qg[(bh * S_ + s) * D_ + d] = f2bf(v * QSCALE_);
                    else
                        Kg[(bh * S_ + s) * D_ + d] = f2bf(v);
                }
            }
        }
    } else {
        // -------- V blocks: LDS-transpose slabs, permuted coalesced stores --
        const int bb = m0 >> 11;
        const int s0 = m0 & 2047;
        const int dth = t >> 3;        // 0..31 : d within slab
        const int sc = t & 7;          // 0..7  : s-chunk of 16
#pragma unroll
        for (int sl = 0; sl < 4; ++sl) {
            __syncthreads();
            if ((wv & 1) == (sl >> 1)) {
#pragma unroll
                for (int q = 0; q < 2; ++q) {
                    const int nt = (sl & 1) * 2 + q;
                    const float bia = biass[wn + nt * 16 + l15];
                    const int dloc = q * 16 + l15;
#pragma unroll
                    for (int mt = 0; mt < 4; ++mt)
#pragma unroll
                        for (int i = 0; i < 4; ++i)
                            Tr[(wm + mt * 16 + g * 4 + i) * 33 + dloc] =
                                acc[mt][nt][i] + bia;
                }
            }
            __syncthreads();
            const int dglob = (n0 - 2048) + sl * 32 + dth;
            const int h = dglob >> 6;
            const int dd = dglob & 63;
            unsigned short* dst =
                Vtg + ((long)(bb * H_ + h) * D_ + dd) * S_ + s0 + sc * 16;
            // key-permuted: dst quads get src quads {0, 2, 1, 3}
            short8 o0, o1;
#pragma unroll
            for (int j = 0; j < 4; ++j) {
                o0[j]     = (short)f2bf(Tr[(sc * 16 + j)      * 33 + dth]);
                o0[4 + j] = (short)f2bf(Tr[(sc * 16 + 8 + j)  * 33 + dth]);
                o1[j]     = (short)f2bf(Tr[(sc * 16 + 4 + j)  * 33 + dth]);
                o1[4 + j] = (short)f2bf(Tr[(sc * 16 + 12 + j) * 33 + dth]);
            }
            *(short8*)dst = o0;
            *(short8*)(dst + 8) = o1;
        }
    }
}

// ---------------------------------------------------------------------------
// Kernel 2: flash attention — R7 wave body (64 q/wave, permuted-V b128
// frags, LDS staging) + in-block key-split x2 for wave supply.
// 4 waves: pair A (waves 0,1) keys 0..1023, pair B (waves 2,3) keys
// 1024..2047; wave (wv&1) owns q sub-tile of 64.  Each pair has its own
// double-buffered K/V LDS (4 x 16KB).  Partials combine by pure addition
// (no-max softmax) through a 32KB overlay on the dead staging LDS.
// Grid (16,32) = 512 blocks x 4 waves = 2048 waves = 2/SIMD.
// ---------------------------------------------------------------------------
__global__ __launch_bounds__(256, 2) void attn_kernel(
    const unsigned short* __restrict__ Qg, const unsigned short* __restrict__ Kg,
    const unsigned short* __restrict__ Vtg, unsigned short* __restrict__ ctx)
{
    __shared__ __attribute__((aligned(16))) unsigned char smem[65536];
    __shared__ float lsumbuf[4][64];
    unsigned short* KsA = (unsigned short*)smem;              // [2][4096]
    unsigned short* VsA = (unsigned short*)(smem + 16384);    // [2][4096]
    unsigned short* KsB = (unsigned short*)(smem + 32768);
    unsigned short* VsB = (unsigned short*)(smem + 49152);
    float* overlay = (float*)smem;    // epilogue reuse: 2 x 4096 floats

    const int t = threadIdx.x;
    const int lane = t & 63;
    const int wv = t >> 6;              // 0..3
    const int pair = wv >> 1;           // key-split half
    const int qsub = wv & 1;            // q sub-tile of 64
    const int qb = blockIdx.x;          // 0..15, q-tile of 128
    const int bh = blockIdx.y;          // 0..31
    const int bb = bh >> 4;
    const int hh = bh & 15;
    const int l31 = lane & 31;
    const int hf = lane >> 5;
    const int rloc = lane >> 3;                      // 0..7 rows per gld16
    const int cg = (lane & 7) ^ (rloc & 7);          // swizzled global chunk
    const int sw = l31 & 7;                          // frag-read swizzle key

    unsigned short* Ks = pair ? KsB : KsA;
    unsigned short* Vs = pair ? VsB : VsA;

    // Q B-frags, once: qa[qh][kc]; wave owns q rows qb*128 + qsub*64 .. +63
    const int qrow0 = qb * 128 + qsub * 64;
    short8 qa[2][4];
#pragma unroll
    for (int qh = 0; qh < 2; ++qh)
#pragma unroll
        for (int kc = 0; kc < 4; ++kc)
            qa[qh][kc] = *(const short8*)(
                Qg + (bh * S_ + qrow0 + qh * 32 + l31) * D_ + kc * 16 + hf * 8);

    f32x16 O[2][2];     // [qh][dt]
    float lsum[2] = {0.f, 0.f};
#pragma unroll
    for (int qh = 0; qh < 2; ++qh)
#pragma unroll
        for (int dt = 0; dt < 2; ++dt)
#pragma unroll
            for (int r = 0; r < 16; ++r) O[qh][dt][r] = 0.f;

    // waves 0,2 stage K for their pair; waves 1,3 stage V.  8 gld16 each.
    auto stage = [&](int it, int bufi) {
        const int tile = pair * 16 + it;
        if ((wv & 1) == 0) {
#pragma unroll
            for (int i = 0; i < 8; ++i)
                gld16(Kg + (bh * S_ + tile * 64 + i * 8 + rloc) * D_ + cg * 8,
                      Ks + bufi * 4096 + i * 512);
        } else {
#pragma unroll
            for (int i = 0; i < 8; ++i)
                gld16(Vtg + (bh * D_ + i * 8 + rloc) * S_ + tile * 64 + cg * 8,
                      Vs + bufi * 4096 + i * 512);
        }
    };

    stage(0, 0);

    for (int it = 0; it < 16; ++it) {
        __syncthreads();               // drains vmcnt; buf[it&1] ready
        if (it + 1 < 16) stage(it + 1, (it + 1) & 1);
        const unsigned short* ks = Ks + (it & 1) * 4096;
        const unsigned short* vs = Vs + (it & 1) * 4096;

        // S^T = K * Q^T : D[m=key][n=q], per (kt, qh)
        f32x16 st[2][2];
#pragma unroll
        for (int kt = 0; kt < 2; ++kt) {
            short8 kf[4];
#pragma unroll
            for (int kc = 0; kc < 4; ++kc)
                kf[kc] = *(const short8*)&ks[(kt * 32 + l31) * 64 + ((2 * kc + hf) ^ sw) * 8];
#pragma unroll
            for (int qh = 0; qh < 2; ++qh) {
                f32x16 s;
#pragma unroll
                for (int r = 0; r < 16; ++r) s[r] = 0.f;
#pragma unroll
                for (int kc = 0; kc < 4; ++kc)
                    s = mfma32(kf[kc], qa[qh][kc], s);
                st[kt][qh] = s;
            }
        }

        // exp2 -> pack -> PV;  vb shared across q-halves (key-permuted b128)
#pragma unroll
        for (int kt = 0; kt < 2; ++kt) {
#pragma unroll
            for (int cp = 0; cp < 2; ++cp) {
                short8 vb[2];
#pragma unroll
                for (int dt = 0; dt < 2; ++dt)
                    vb[dt] = *(const short8*)&vs[(dt * 32 + l31) * 64 +
                                                 ((4 * kt + 2 * cp + hf) ^ sw) * 8];
#pragma unroll
                for (int qh = 0; qh < 2; ++qh) {
                    float p[8];
#pragma unroll
                    for (int j = 0; j < 8; ++j)
                        p[j] = __builtin_amdgcn_exp2f(st[kt][qh][8 * cp + j]);
                    lsum[qh] += (p[0] + p[1]) + (p[2] + p[3]) +
                                (p[4] + p[5]) + (p[6] + p[7]);
                    union { short8 s8; u32 u[4]; } pa;
                    pa.u[0] = pkbf(p[0], p[1]);
                    pa.u[1] = pkbf(p[2], p[3]);
                    pa.u[2] = pkbf(p[4], p[5]);
                    pa.u[3] = pkbf(p[6], p[7]);
#pragma unroll
                    for (int dt = 0; dt < 2; ++dt)
                        O[qh][dt] = mfma32(pa.s8, vb[dt], O[qh][dt]);
                }
            }
        }
    }

    // partial denominators: fold hf key-halves, publish per wave
#pragma unroll
    for (int qh = 0; qh < 2; ++qh) {
        float s = lsum[qh] + __shfl_xor(lsum[qh], 32);
        if (hf == 0) lsumbuf[wv][qh * 32 + l31] = s;
    }
    __syncthreads();                   // staging dead; lsums published

    if (pair == 1) {
        // pair B: publish O partials into overlay slab (qsub)
#pragma unroll
        for (int qh = 0; qh < 2; ++qh)
#pragma unroll
            for (int dt = 0; dt < 2; ++dt)
#pragma unroll
                for (int r = 0; r < 16; ++r) {
                    const int ql = qh * 32 + 4 * hf + (r & 3) + 8 * (r >> 2);
                    overlay[qsub * 4096 + ql * 64 + dt * 32 + l31] = O[qh][dt][r];
                }
    }
    __syncthreads();

    if (pair == 0) {
        // pair A: combine, normalize, store ctx[b, s, h*64+d]
        float inv[2][16];
#pragma unroll
        for (int qh = 0; qh < 2; ++qh)
#pragma unroll
            for (int r = 0; r < 16; ++r) {
                const int ql = qh * 32 + 4 * hf + (r & 3) + 8 * (r >> 2);
                inv[qh][r] = 1.0f / (lsumbuf[wv][ql] + lsumbuf[wv + 2][ql]);
            }
#pragma unroll
        for (int qh = 0; qh < 2; ++qh)
#pragma unroll
            for (int dt = 0; dt < 2; ++dt)
#pragma unroll
                for (int r = 0; r < 16; ++r) {
                    const int ql = qh * 32 + 4 * hf + (r & 3) + 8 * (r >> 2);
                    const float v = (O[qh][dt][r] +
                        overlay[qsub * 4096 + ql * 64 + dt * 32 + l31]) * inv[qh][r];
                    const int s = qb * 128 + qsub * 64 + ql;
                    ctx[(bb * S_ + s) * E_ + hh * D_ + dt * 32 + l31] = f2bf(v);
                }
    }
}

// ---------------------------------------------------------------------------
// Kernel 3: output projection, 128x64 tiles, BK=32 (grid 512 = 2 blocks/CU).
// ---------------------------------------------------------------------------
__global__ __launch_bounds__(256) void out_gemm_kernel(
    const unsigned short* __restrict__ ctxg, const unsigned short* __restrict__ w,
    const float* __restrict__ bias, float* __restrict__ out)
{
    __shared__ __attribute__((aligned(16))) unsigned short As[128 * 32];
    __shared__ __attribute__((aligned(16))) unsigned short Bs[64 * 32];
    __shared__ float biass[64];

    const int t = threadIdx.x;
    const int m0 = blockIdx.x * 128;
    const int n0 = blockIdx.y * 64;
    const int lane = t & 63;
    const int wv = t >> 6;
    const int g = lane >> 4;
    const int l15 = lane & 15;
    const int wm = (wv >> 1) * 64;
    const int wn = (wv & 1) * 32;
    const int rloc = lane >> 2;
    const int cg = (lane & 3) ^ ((lane >> 3) & 3);
    const int rsw = (g ^ ((l15 >> 1) & 3)) * 8;

    if (t < 64) biass[t] = bias[n0 + t];

    f32x4 acc[4][2];
#pragma unroll
    for (int i = 0; i < 4; ++i)
#pragma unroll
        for (int j = 0; j < 2; ++j)
            acc[i][j] = (f32x4){0.f, 0.f, 0.f, 0.f};

    for (int kt = 0; kt < E_; kt += 32) {
        __syncthreads();
#pragma unroll
        for (int j = 0; j < 2; ++j) {
            const int rb = 32 * wv + 16 * j;
            gld16(ctxg + (m0 + rb + rloc) * E_ + kt + cg * 8, &As[rb * 32]);
        }
        {
            const int rb = 16 * wv;
            gld16(w + (n0 + rb + rloc) * E_ + kt + cg * 8, &Bs[rb * 32]);
        }
        __syncthreads();

        short8 af[4], bf[2];
#pragma unroll
        for (int mt = 0; mt < 4; ++mt)
            af[mt] = *(const short8*)&As[(wm + mt * 16 + l15) * 32 + rsw];
#pragma unroll
        for (int nt = 0; nt < 2; ++nt)
            bf[nt] = *(const short8*)&Bs[(wn + nt * 16 + l15) * 32 + rsw];
#pragma unroll
        for (int mt = 0; mt < 4; ++mt)
#pragma unroll
            for (int nt = 0; nt < 2; ++nt)
                acc[mt][nt] = mfma16(af[mt], bf[nt], acc[mt][nt]);
    }

#pragma unroll
    for (int mt = 0; mt < 4; ++mt) {
#pragma unroll
        for (int nt = 0; nt < 2; ++nt) {
            const int col = n0 + wn + nt * 16 + l15;
            const float bia = biass[col - n0];
#pragma unroll
            for (int i = 0; i < 4; ++i) {
                const int row = m0 + wm + mt * 16 + g * 4 + i;
                out[row * E_ + col] = acc[mt][nt][i] + bia;
            }
        }
    }
}

extern "C" void kernel_launch(void* const* d_in, const int* in_sizes, int n_in,
                              void* d_out, int out_size, void* d_ws, size_t ws_size,
                              hipStream_t stream) {
    const float* x    = (const float*)d_in[0];
    const float* wqkv = (const float*)d_in[1];
    const float* wout = (const float*)d_in[2];
    const float* bqkv = (const float*)d_in[3];
    const float* bout = (const float*)d_in[4];

    unsigned short* Q   = (unsigned short*)d_ws;       // 8 MB
    unsigned short* K   = Q + 4194304;                 // 8 MB
    unsigned short* Vt  = K + 4194304;                 // 8 MB (key-permuted)
    unsigned short* ctx = Vt + 4194304;                // 8 MB (aliased with xb)
    unsigned short* xb  = ctx;                         // dead before attn writes ctx
    unsigned short* wqb = ctx + 4194304;               // 6 MB
    unsigned short* wob = wqb + 3145728;               // 2 MB  (total 40 MB)

    cvt_kernel<<<4096, 256, 0, stream>>>(x, wqkv, wout, xb, wqb, wob);
    qkv_gemm_kernel<<<dim3(32, 24), 256, 0, stream>>>(xb, wqb, bqkv, Q, K, Vt);
    attn_kernel<<<dim3(16, 32), 256, 0, stream>>>(Q, K, Vt, ctx);
    out_gemm_kernel<<<dim3(32, 16), 256, 0, stream>>>(ctx, wob, bout, (float*)d_out);
}